// Round 9
// baseline (273.339 us; speedup 1.0000x reference)
//
#include <hip/hip_runtime.h>
#include <hip/hip_bf16.h>

#define B_   8
#define N_   8192
#define S_   2048
#define D1_  128
#define D2_  256
#define CIN_ 384
#define C1_  256
#define C2_  128
#define ROWS_ (B_ * N_)   // 65536

typedef __attribute__((ext_vector_type(8))) short short8v;   // 8 bf16 (4 VGPRs)
typedef __attribute__((ext_vector_type(4))) float f32x4;     // MFMA acc

__device__ inline unsigned short f2bf(float x) {
    __hip_bfloat16 h = __float2bfloat16(x);   // RNE
    unsigned short u;
    __builtin_memcpy(&u, &h, 2);
    return u;
}
__device__ inline float bf2f(unsigned short u) {
    unsigned int x = ((unsigned int)u) << 16;
    float f;
    __builtin_memcpy(&f, &x, 4);
    return f;
}
__device__ inline unsigned int f2u(float x) { unsigned int u; __builtin_memcpy(&u, &x, 4); return u; }
__device__ inline float u2f(unsigned int u) { float x; __builtin_memcpy(&x, &u, 4); return x; }

// ---------------------------------------------------------------------------
// Pack xyz2 -> {x, y, z, r2} float4 in GLOBAL memory (candidates then stream
// through the SCALAR path in nn3 — wave-uniform address -> s_load, zero DS
// traffic). r2 formula bit-identical to all passing rounds.
// ---------------------------------------------------------------------------
__global__ __launch_bounds__(256) void pack_kernel(
    const float* __restrict__ xyz2, float4* __restrict__ pk)
{
#pragma clang fp contract(off)
    int i = blockIdx.x * 256 + threadIdx.x;   // 0 .. B_*S_-1
    float a = xyz2[i * 3 + 0], c = xyz2[i * 3 + 1], d = xyz2[i * 3 + 2];
    float4 v; v.x = a; v.y = c; v.z = d; v.w = (a * a + c * c) + d * d;
    pk[i] = v;
}

// ---------------------------------------------------------------------------
// 3-NN, exact two-pass scheme (pass A values via fmin+2xfmed3; pass B index
// recovery by class — logic identical to the passing round 8). Candidate
// reads are wave-uniform loads from packed GLOBAL array -> scalar K$ path,
// removing the DS-pipe bottleneck (round 8: ~82µs of broadcast ds_read_b128).
// 512 blocks (2/CU), 128 queries x 8 chunks of 256 candidates.
// Distance arithmetic bit-identical to all passing rounds.
// ---------------------------------------------------------------------------
__global__ __launch_bounds__(1024) void nn3_kernel(
    const float* __restrict__ xyz1, const float4* __restrict__ pk,
    int* __restrict__ nidx, float* __restrict__ nw)
{
#pragma clang fp contract(off)
    __shared__ unsigned int pa[8][128][3];     // 12 KiB passA values / passB class-1 idx
    __shared__ int   pb[8][128][2];            // 8 KiB passB class-2 idx
    __shared__ int   pc[8][128];               // 4 KiB passB class-3 idx
    __shared__ float fvv[128][3];              // 1.5 KiB final v1,v2,v3 broadcast
    const int tid = threadIdx.x;
    const int b = blockIdx.y;
    const int q = tid & 127;
    const int chunk = tid >> 7;                // 0..7 (wave-uniform)
    const float4* __restrict__ cand = pk + (size_t)b * S_;
    const int n = blockIdx.x * 128 + q;
    const float* p = xyz1 + ((size_t)b * N_ + n) * 3;
    const float px = p[0], py = p[1], pz = p[2];
    const float r1 = (px * px + py * py) + pz * pz;
    const int s0 = chunk * 256;

    // ---- pass A: exact top-3 values ----
    float e1 = 3.4e38f, e2 = 3.4e38f, e3 = 3.4e38f;
#pragma unroll 8
    for (int k = 0; k < 256; ++k) {
        float4 qq = cand[s0 + k];              // uniform -> s_load_dwordx4
        float dot = (px * qq.x + py * qq.y) + pz * qq.z;
        float d = (r1 - 2.0f * dot) + qq.w;
        float n1 = fminf(e1, d);
        float n2 = __builtin_amdgcn_fmed3f(d, e1, e2);
        float n3 = __builtin_amdgcn_fmed3f(d, e2, e3);
        e1 = n1; e2 = n2; e3 = n3;
    }
    pa[chunk][q][0] = f2u(e1); pa[chunk][q][1] = f2u(e2); pa[chunk][q][2] = f2u(e3);
    __syncthreads();

    float v1f = 0.f, v2f = 0.f, v3f = 0.f;
    if (tid < 128) {
        float m1 = u2f(pa[0][tid][0]), m2 = u2f(pa[0][tid][1]), m3 = u2f(pa[0][tid][2]);
#pragma unroll
        for (int c = 1; c < 8; ++c)
#pragma unroll
            for (int e = 0; e < 3; ++e) {
                float x = u2f(pa[c][tid][e]);
                float n1 = fminf(m1, x);
                float n2 = __builtin_amdgcn_fmed3f(x, m1, m2);
                float n3 = __builtin_amdgcn_fmed3f(x, m2, m3);
                m1 = n1; m2 = n2; m3 = n3;
            }
        v1f = m1; v2f = m2; v3f = m3;
        fvv[tid][0] = m1; fvv[tid][1] = m2; fvv[tid][2] = m3;
    }
    __syncthreads();
    const float t1 = fvv[q][0], t2 = fvv[q][1], t3 = fvv[q][2];

    // ---- pass B: index recovery, per-class min-index tracking ----
    int a1 = 0x7FFFFFFF, a2 = 0x7FFFFFFF, a3 = 0x7FFFFFFF;  // class d==t1
    int b1 = 0x7FFFFFFF, b2 = 0x7FFFFFFF;                    // class d==t2
    int c1 = 0x7FFFFFFF;                                     // class d==t3
#pragma unroll 4
    for (int k = 0; k < 256; ++k) {
        float4 qq = cand[s0 + k];
        float dot = (px * qq.x + py * qq.y) + pz * qq.z;
        float d = (r1 - 2.0f * dot) + qq.w;
        if (d <= t3) {                         // ~9% of wave-iterations active
            const int s = s0 + k;
            int u1 = (d == t1) ? s : 0x7FFFFFFF;
            int u2 = (d == t2) ? s : 0x7FFFFFFF;
            int na3 = min(a3, max(a2, u1));
            int na2 = min(a2, max(a1, u1));
            a1 = min(a1, u1); a2 = na2; a3 = na3;
            int nb2 = min(b2, max(b1, u2));
            b1 = min(b1, u2); b2 = nb2;
            c1 = (d == t3) ? min(c1, s) : c1;
        }
    }
    pa[chunk][q][0] = (unsigned)a1; pa[chunk][q][1] = (unsigned)a2; pa[chunk][q][2] = (unsigned)a3;
    pb[chunk][q][0] = b1; pb[chunk][q][1] = b2;
    pc[chunk][q] = c1;
    __syncthreads();

    if (tid < 128) {
        int A1 = 0x7FFFFFFF, A2 = 0x7FFFFFFF, A3 = 0x7FFFFFFF;
        int B1 = 0x7FFFFFFF, B2 = 0x7FFFFFFF;
        int C1m = 0x7FFFFFFF;
#pragma unroll
        for (int c = 0; c < 8; ++c) {
#pragma unroll
            for (int e = 0; e < 3; ++e) {
                int x = (int)pa[c][tid][e];
                int nA3 = min(A3, max(A2, x));
                int nA2 = min(A2, max(A1, x));
                A1 = min(A1, x); A2 = nA2; A3 = nA3;
            }
#pragma unroll
            for (int e = 0; e < 2; ++e) {
                int x = pb[c][tid][e];
                int nB2 = min(B2, max(B1, x));
                B1 = min(B1, x); B2 = nB2;
            }
            C1m = min(C1m, pc[c][tid]);
        }
        // 4-case lexicographic assembly (== top_k lower-index-wins)
        int j1 = A1, j2, j3;
        if (v2f == v1f) j2 = A2; else j2 = B1;
        if (v3f == v2f) j3 = (v2f == v1f) ? A3 : B2;
        else            j3 = C1m;
        float ra = 1.0f / (v1f + 1e-8f);
        float rb = 1.0f / (v2f + 1e-8f);
        float rc = 1.0f / (v3f + 1e-8f);
        float sum = (ra + rb) + rc;
        size_t o = ((size_t)b * N_ + blockIdx.x * 128 + tid) * 3;
        nidx[o + 0] = j1; nidx[o + 1] = j2; nidx[o + 2] = j3;
        nw[o + 0] = ra / sum; nw[o + 1] = rb / sum; nw[o + 2] = rc / sum;
    }
}

// both weight tensors f32 -> bf16 in one launch
__global__ void cvtw_kernel(const float* __restrict__ w1, const float* __restrict__ w2,
                            unsigned short* __restrict__ w1b, unsigned short* __restrict__ w2b)
{
    int i = blockIdx.x * 256 + threadIdx.x;
    if (i < C1_ * CIN_) w1b[i] = f2bf(w1[i]);
    else {
        int j = i - C1_ * CIN_;
        if (j < C2_ * C1_) w2b[j] = f2bf(w2[j]);
    }
}

// ---------------------------------------------------------------------------
// Build A1 bf16 [ROWS][384] = concat(points1, interp(points2)).
// ---------------------------------------------------------------------------
__global__ __launch_bounds__(256) void a1build_kernel(
    const float* __restrict__ p1, const float* __restrict__ p2,
    const int* __restrict__ nidx, const float* __restrict__ nw,
    unsigned short* __restrict__ A1)
{
    const int row = (blockIdx.x & 7) * N_ + (blockIdx.x >> 3);  // batch = xcd
    const int c = threadIdx.x;
    const int b = row >> 13;
    const int i0 = nidx[row * 3 + 0], i1 = nidx[row * 3 + 1], i2 = nidx[row * 3 + 2];
    const float w0 = nw[row * 3 + 0], w1 = nw[row * 3 + 1], w2 = nw[row * 3 + 2];
    const float* base = p2 + (size_t)b * S_ * D2_;
    float v = base[(size_t)i0 * D2_ + c] * w0
            + base[(size_t)i1 * D2_ + c] * w1
            + base[(size_t)i2 * D2_ + c] * w2;
    unsigned short* arow = A1 + (size_t)row * CIN_;
    arow[D1_ + c] = f2bf(v);
    if (c < D1_) arow[c] = f2bf(p1[(size_t)row * D1_ + c]);
}

// ---------------------------------------------------------------------------
// bf16 MFMA GEMM, pure global_load_lds staging, fused bias + BN-stats.
// ---------------------------------------------------------------------------
template <int K, int COUT, int WRITE_BF16, int GRIDCOLS>
__global__ __launch_bounds__(256) void gemm_mfma_kernel(
    const unsigned short* __restrict__ A,   // [ROWS][K] bf16
    const unsigned short* __restrict__ W,   // [COUT][K] bf16
    const float* __restrict__ bias,         // [COUT]
    void* __restrict__ out,                 // [ROWS][COUT] bf16 or f32
    float* __restrict__ sums, float* __restrict__ ssqs)
{
    __shared__ unsigned short As[4][128][8];   // 8 KiB
    __shared__ unsigned short Bs[4][128][8];   // 8 KiB
    __shared__ float csum[128], csq[128];
    const int tid = threadIdx.x;
    const int wave = tid >> 6, lane = tid & 63;
    const int chunkw = (blockIdx.x & 7) * (gridDim.x >> 3) + (blockIdx.x >> 3);
    const int r0 = (chunkw / GRIDCOLS) * 128;
    const int n0 = (chunkw % GRIDCOLS) * 128;
    const int wr = wave >> 1, wc = wave & 1;
    const int kh = lane >> 4, l16 = lane & 15;

    if (tid < 128) { csum[tid] = 0.f; csq[tid] = 0.f; }

    f32x4 acc[4][4];
#pragma unroll
    for (int m = 0; m < 4; ++m)
#pragma unroll
        for (int n = 0; n < 4; ++n)
            acc[m][n] = (f32x4){0.f, 0.f, 0.f, 0.f};

    const int slotbase = wave * 64;

    for (int k0 = 0; k0 < K; k0 += 32) {
        __syncthreads();
#pragma unroll
        for (int p = 0; p < 2; ++p) {
            const int sb = p * 256 + slotbase;
            const int s = sb + lane;
            const int kg = s >> 7, i = s & 127;
            const unsigned short* gA = A + (size_t)(r0 + i) * K + k0 + kg * 8;
            const unsigned short* gB = W + (size_t)(n0 + i) * K + k0 + kg * 8;
            __builtin_amdgcn_global_load_lds(
                (const __attribute__((address_space(1))) void*)gA,
                (__attribute__((address_space(3))) void*)(&As[0][0][0] + (size_t)sb * 8),
                16, 0, 0);
            __builtin_amdgcn_global_load_lds(
                (const __attribute__((address_space(1))) void*)gB,
                (__attribute__((address_space(3))) void*)(&Bs[0][0][0] + (size_t)sb * 8),
                16, 0, 0);
        }
        __syncthreads();

        short8v af[4], bf[4];
#pragma unroll
        for (int m = 0; m < 4; ++m)
            af[m] = *(const short8v*)&As[kh][wr * 64 + m * 16 + l16][0];
#pragma unroll
        for (int n = 0; n < 4; ++n)
            bf[n] = *(const short8v*)&Bs[kh][wc * 64 + n * 16 + l16][0];
#pragma unroll
        for (int m = 0; m < 4; ++m)
#pragma unroll
            for (int n = 0; n < 4; ++n)
                acc[m][n] = __builtin_amdgcn_mfma_f32_16x16x32_bf16(
                    af[m], bf[n], acc[m][n], 0, 0, 0);
    }

#pragma unroll
    for (int n = 0; n < 4; ++n) {
        const int cl = wc * 64 + n * 16 + l16;
        const int col = n0 + cl;
        const float bv = bias[col];
        float s = 0.f, qs = 0.f;
#pragma unroll
        for (int m = 0; m < 4; ++m) {
            const int rowb = r0 + wr * 64 + m * 16 + kh * 4;
#pragma unroll
            for (int j = 0; j < 4; ++j) {
                const float v = acc[m][n][j] + bv;
                s += v; qs += v * v;
                if (WRITE_BF16)
                    ((unsigned short*)out)[(size_t)(rowb + j) * COUT + col] = f2bf(v);
                else
                    ((float*)out)[(size_t)(rowb + j) * COUT + col] = v;
            }
        }
        atomicAdd(&csum[cl], s);
        atomicAdd(&csq[cl], qs);
    }
    __syncthreads();
    if (tid < 128) {
        atomicAdd(&sums[n0 + tid], csum[tid]);
        atomicAdd(&ssqs[n0 + tid], csq[tid]);
    }
}

__global__ void finalize_kernel(const float* __restrict__ sums,
                                const float* __restrict__ ssqs,
                                const float* __restrict__ g,
                                const float* __restrict__ be,
                                float* __restrict__ scale,
                                float* __restrict__ shift, int C, float invCnt)
{
    int c = threadIdx.x;
    if (c < C) {
        float mu = sums[c] * invCnt;
        float var = ssqs[c] * invCnt - mu * mu;
        float sc = g[c] / sqrtf(var + 1e-5f);
        scale[c] = sc;
        shift[c] = be[c] - mu * sc;
    }
}

// y1 bf16 -> a2 bf16 : relu(y*scale+shift), 8 elems/thread
__global__ __launch_bounds__(256) void bnconv_kernel(
    const unsigned short* __restrict__ y, const float* __restrict__ scale,
    const float* __restrict__ shift, unsigned short* __restrict__ a2)
{
    const int i = blockIdx.x * 256 + threadIdx.x;    // short8 index
    const int c0 = (i * 8) & (C1_ - 1);
    short8v v = ((const short8v*)y)[i];
    float4 sca = *(const float4*)(scale + c0);
    float4 scb = *(const float4*)(scale + c0 + 4);
    float4 sha = *(const float4*)(shift + c0);
    float4 shb = *(const float4*)(shift + c0 + 4);
    float sc[8] = {sca.x, sca.y, sca.z, sca.w, scb.x, scb.y, scb.z, scb.w};
    float sh[8] = {sha.x, sha.y, sha.z, sha.w, shb.x, shb.y, shb.z, shb.w};
    short8v r;
#pragma unroll
    for (int j = 0; j < 8; ++j) {
        float f = bf2f((unsigned short)v[j]);
        f = fmaxf(fmaf(f, sc[j], sh[j]), 0.0f);
        r[j] = (short)f2bf(f);
    }
    ((short8v*)a2)[i] = r;
}

// final BN+ReLU, f32 out
__global__ __launch_bounds__(256) void bnrelu_store_kernel(
    const float* __restrict__ y, const float* __restrict__ scale,
    const float* __restrict__ shift, float* __restrict__ out)
{
    int i = blockIdx.x * 256 + threadIdx.x;   // float4 index
    float4 v = ((const float4*)y)[i];
    int o = (i * 4) & (C2_ - 1);
    float4 sc = *(const float4*)(scale + o);
    float4 sh = *(const float4*)(shift + o);
    float4 r;
    r.x = fmaxf(fmaf(v.x, sc.x, sh.x), 0.0f);
    r.y = fmaxf(fmaf(v.y, sc.y, sh.y), 0.0f);
    r.z = fmaxf(fmaf(v.z, sc.z, sh.z), 0.0f);
    r.w = fmaxf(fmaf(v.w, sc.w, sh.w), 0.0f);
    ((float4*)out)[i] = r;
}

extern "C" void kernel_launch(void* const* d_in, const int* in_sizes, int n_in,
                              void* d_out, int out_size, void* d_ws, size_t ws_size,
                              hipStream_t stream)
{
    const float* xyz1    = (const float*)d_in[0];
    const float* xyz2    = (const float*)d_in[1];
    const float* points1 = (const float*)d_in[2];
    const float* points2 = (const float*)d_in[3];
    const float* w1  = (const float*)d_in[4];
    const float* b1  = (const float*)d_in[5];
    const float* g1  = (const float*)d_in[6];
    const float* be1 = (const float*)d_in[7];
    const float* w2  = (const float*)d_in[8];
    const float* b2  = (const float*)d_in[9];
    const float* g2  = (const float*)d_in[10];
    const float* be2 = (const float*)d_in[11];
    float* out = (float*)d_out;

    char* w = (char*)d_ws;
    unsigned short* A1  = (unsigned short*)w;                    // 50,331,648 B
    unsigned short* y1b = (unsigned short*)(w + 50331648);       // 33,554,432 B
    unsigned short* a2b = (unsigned short*)(w + 83886080);       // 33,554,432 B
    float*          y2  = (float*)A1;                            // reuse region 0
    char* tail = w + 117440512;
    int*   nidx = (int*)tail;                                    // 786,432 B
    float* nw   = (float*)(tail + 786432);                       // 786,432 B
    unsigned short* w1b = (unsigned short*)(tail + 1572864);     // 196,608 B
    unsigned short* w2b = (unsigned short*)(tail + 1769472);     // 65,536 B
    float* sum1   = (float*)(tail + 1835008);
    float* ssq1   = sum1 + 256;
    float* sum2   = ssq1 + 256;
    float* ssq2   = sum2 + 128;
    float* scale1 = ssq2 + 128;
    float* shift1 = scale1 + 256;
    float* scale2 = shift1 + 256;
    float* shift2 = scale2 + 128;
    float4* pk    = (float4*)(tail + 1843200);                   // 262,144 B

    hipMemsetAsync(sum1, 0, (256 + 256 + 128 + 128) * sizeof(float), stream);

    cvtw_kernel<<<dim3((C1_ * CIN_ + C2_ * C1_ + 255) / 256), 256, 0, stream>>>(w1, w2, w1b, w2b);
    pack_kernel<<<dim3(B_ * S_ / 256), 256, 0, stream>>>(xyz2, pk);

    nn3_kernel<<<dim3(N_ / 128, B_), 1024, 0, stream>>>(xyz1, pk, nidx, nw);
    a1build_kernel<<<dim3(ROWS_), 256, 0, stream>>>(points1, points2, nidx, nw, A1);

    gemm_mfma_kernel<CIN_, C1_, 1, 2><<<dim3(ROWS_ / 128 * 2), 256, 0, stream>>>(
        A1, w1b, b1, (void*)y1b, sum1, ssq1);
    finalize_kernel<<<1, 256, 0, stream>>>(sum1, ssq1, g1, be1, scale1, shift1, C1_, 1.0f / ROWS_);
    bnconv_kernel<<<dim3(ROWS_ * C1_ / 8 / 256), 256, 0, stream>>>(y1b, scale1, shift1, a2b);

    gemm_mfma_kernel<C1_, C2_, 0, 1><<<dim3(ROWS_ / 128), 256, 0, stream>>>(
        a2b, w2b, b2, (void*)y2, sum2, ssq2);
    finalize_kernel<<<1, 256, 0, stream>>>(sum2, ssq2, g2, be2, scale2, shift2, C2_, 1.0f / ROWS_);

    bnrelu_store_kernel<<<dim3(ROWS_ * C2_ / 4 / 256), 256, 0, stream>>>(y2, scale2, shift2, out);
}

// Round 10
// 207.504 us; speedup vs baseline: 1.3173x; 1.3173x over previous
//
#include <hip/hip_runtime.h>
#include <hip/hip_bf16.h>

#define B_   8
#define N_   8192
#define S_   2048
#define D1_  128
#define D2_  256
#define CIN_ 384
#define C1_  256
#define C2_  128
#define ROWS_ (B_ * N_)   // 65536

typedef __attribute__((ext_vector_type(8))) short short8v;   // 8 bf16 (4 VGPRs)
typedef __attribute__((ext_vector_type(4))) float f32x4;     // MFMA acc
typedef __attribute__((ext_vector_type(16))) float f32x16;   // s_load_dwordx16

__device__ inline unsigned short f2bf(float x) {
    __hip_bfloat16 h = __float2bfloat16(x);   // RNE
    unsigned short u;
    __builtin_memcpy(&u, &h, 2);
    return u;
}
__device__ inline float bf2f(unsigned short u) {
    unsigned int x = ((unsigned int)u) << 16;
    float f;
    __builtin_memcpy(&f, &x, 4);
    return f;
}
__device__ inline unsigned int f2u(float x) { unsigned int u; __builtin_memcpy(&u, &x, 4); return u; }
__device__ inline float u2f(unsigned int u) { float x; __builtin_memcpy(&x, &u, 4); return x; }

// ---------------------------------------------------------------------------
// Pack xyz2 -> {x, y, z, r2} float4 in GLOBAL memory. r2 formula bit-identical
// to all passing rounds (this exact kernel passed round 9).
// ---------------------------------------------------------------------------
__global__ __launch_bounds__(256) void pack_kernel(
    const float* __restrict__ xyz2, float4* __restrict__ pk)
{
#pragma clang fp contract(off)
    int i = blockIdx.x * 256 + threadIdx.x;   // 0 .. B_*S_-1
    float a = xyz2[i * 3 + 0], c = xyz2[i * 3 + 1], d = xyz2[i * 3 + 2];
    float4 v; v.x = a; v.y = c; v.z = d; v.w = (a * a + c * c) + d * d;
    pk[i] = v;
}

// ---------------------------------------------------------------------------
// 3-NN, exact two-pass scheme (logic byte-identical to passing rounds 7/8/9).
// Candidate delivery via FORCED scalar loads: inline-asm s_load_dwordx16 x2
// (8 candidates/group) + bundled s_waitcnt. Scalar pipe, zero DS, zero VMEM
// for candidates. 512 blocks (2/CU, 8 waves/SIMD), 128 queries x 8 chunks.
// Distance arithmetic bit-identical to all passing rounds.
// ---------------------------------------------------------------------------
__global__ __launch_bounds__(1024) void nn3_kernel(
    const float* __restrict__ xyz1, const float4* __restrict__ pk,
    int* __restrict__ nidx, float* __restrict__ nw)
{
#pragma clang fp contract(off)
    __shared__ unsigned int pa[8][128][3];     // 12 KiB passA values / passB class-1 idx
    __shared__ int   pb[8][128][2];            // 8 KiB passB class-2 idx
    __shared__ int   pc[8][128];               // 4 KiB passB class-3 idx
    __shared__ float fvv[128][3];              // 1.5 KiB final v1,v2,v3 broadcast
    const int tid = threadIdx.x;
    const int b = blockIdx.y;
    const int q = tid & 127;
    const int chunk = tid >> 7;                // 0..7 (wave-uniform: 128-aligned spans)
    const int s0 = chunk * 256;
    // force the per-wave-uniform chunk offset into an SGPR
    const unsigned s0u = __builtin_amdgcn_readfirstlane((unsigned)s0);
    const char* cp = (const char*)(pk + (size_t)b * S_) + (size_t)s0u * 16u;

    const int n = blockIdx.x * 128 + q;
    const float* p = xyz1 + ((size_t)b * N_ + n) * 3;
    const float px = p[0], py = p[1], pz = p[2];
    const float r1 = (px * px + py * py) + pz * pz;

    // ---- pass A: exact top-3 values (fmin + 2x fmed3 per candidate) ----
    float e1 = 3.4e38f, e2 = 3.4e38f, e3 = 3.4e38f;
    for (int g = 0; g < 32; ++g) {
        f32x16 c0, c1;
        asm volatile("s_load_dwordx16 %0, %2, 0\n\t"
                     "s_load_dwordx16 %1, %2, 64\n\t"
                     "s_waitcnt lgkmcnt(0)"
                     : "=&s"(c0), "=&s"(c1) : "s"(cp + (size_t)g * 128));
#pragma unroll
        for (int j = 0; j < 8; ++j) {
            float sx = (j < 4) ? c0[4 * j + 0] : c1[4 * (j - 4) + 0];
            float sy = (j < 4) ? c0[4 * j + 1] : c1[4 * (j - 4) + 1];
            float sz = (j < 4) ? c0[4 * j + 2] : c1[4 * (j - 4) + 2];
            float sr = (j < 4) ? c0[4 * j + 3] : c1[4 * (j - 4) + 3];
            float dot = (px * sx + py * sy) + pz * sz;
            float d = (r1 - 2.0f * dot) + sr;
            float n1 = fminf(e1, d);
            float n2 = __builtin_amdgcn_fmed3f(d, e1, e2);
            float n3 = __builtin_amdgcn_fmed3f(d, e2, e3);
            e1 = n1; e2 = n2; e3 = n3;
        }
    }
    pa[chunk][q][0] = f2u(e1); pa[chunk][q][1] = f2u(e2); pa[chunk][q][2] = f2u(e3);
    __syncthreads();

    float v1f = 0.f, v2f = 0.f, v3f = 0.f;
    if (tid < 128) {
        float m1 = u2f(pa[0][tid][0]), m2 = u2f(pa[0][tid][1]), m3 = u2f(pa[0][tid][2]);
#pragma unroll
        for (int c = 1; c < 8; ++c)
#pragma unroll
            for (int e = 0; e < 3; ++e) {
                float x = u2f(pa[c][tid][e]);
                float n1 = fminf(m1, x);
                float n2 = __builtin_amdgcn_fmed3f(x, m1, m2);
                float n3 = __builtin_amdgcn_fmed3f(x, m2, m3);
                m1 = n1; m2 = n2; m3 = n3;
            }
        v1f = m1; v2f = m2; v3f = m3;
        fvv[tid][0] = m1; fvv[tid][1] = m2; fvv[tid][2] = m3;
    }
    __syncthreads();
    const float t1 = fvv[q][0], t2 = fvv[q][1], t3 = fvv[q][2];

    // ---- pass B: index recovery, per-class min-index tracking ----
    int a1 = 0x7FFFFFFF, a2 = 0x7FFFFFFF, a3 = 0x7FFFFFFF;  // class d==t1
    int b1 = 0x7FFFFFFF, b2 = 0x7FFFFFFF;                    // class d==t2
    int c1m = 0x7FFFFFFF;                                    // class d==t3
    for (int g = 0; g < 32; ++g) {
        f32x16 c0, c1;
        asm volatile("s_load_dwordx16 %0, %2, 0\n\t"
                     "s_load_dwordx16 %1, %2, 64\n\t"
                     "s_waitcnt lgkmcnt(0)"
                     : "=&s"(c0), "=&s"(c1) : "s"(cp + (size_t)g * 128));
#pragma unroll
        for (int j = 0; j < 8; ++j) {
            float sx = (j < 4) ? c0[4 * j + 0] : c1[4 * (j - 4) + 0];
            float sy = (j < 4) ? c0[4 * j + 1] : c1[4 * (j - 4) + 1];
            float sz = (j < 4) ? c0[4 * j + 2] : c1[4 * (j - 4) + 2];
            float sr = (j < 4) ? c0[4 * j + 3] : c1[4 * (j - 4) + 3];
            float dot = (px * sx + py * sy) + pz * sz;
            float d = (r1 - 2.0f * dot) + sr;
            if (d <= t3) {                     // rare: ~3 hits per query total
                const int s = s0 + g * 8 + j;
                int u1 = (d == t1) ? s : 0x7FFFFFFF;
                int u2 = (d == t2) ? s : 0x7FFFFFFF;
                int na3 = min(a3, max(a2, u1));
                int na2 = min(a2, max(a1, u1));
                a1 = min(a1, u1); a2 = na2; a3 = na3;
                int nb2 = min(b2, max(b1, u2));
                b1 = min(b1, u2); b2 = nb2;
                c1m = (d == t3) ? min(c1m, s) : c1m;
            }
        }
    }
    pa[chunk][q][0] = (unsigned)a1; pa[chunk][q][1] = (unsigned)a2; pa[chunk][q][2] = (unsigned)a3;
    pb[chunk][q][0] = b1; pb[chunk][q][1] = b2;
    pc[chunk][q] = c1m;
    __syncthreads();

    if (tid < 128) {
        int A1 = 0x7FFFFFFF, A2 = 0x7FFFFFFF, A3 = 0x7FFFFFFF;
        int B1 = 0x7FFFFFFF, B2 = 0x7FFFFFFF;
        int C1m = 0x7FFFFFFF;
#pragma unroll
        for (int c = 0; c < 8; ++c) {
#pragma unroll
            for (int e = 0; e < 3; ++e) {
                int x = (int)pa[c][tid][e];
                int nA3 = min(A3, max(A2, x));
                int nA2 = min(A2, max(A1, x));
                A1 = min(A1, x); A2 = nA2; A3 = nA3;
            }
#pragma unroll
            for (int e = 0; e < 2; ++e) {
                int x = pb[c][tid][e];
                int nB2 = min(B2, max(B1, x));
                B1 = min(B1, x); B2 = nB2;
            }
            C1m = min(C1m, pc[c][tid]);
        }
        // 4-case lexicographic assembly (== top_k lower-index-wins)
        int j1 = A1, j2, j3;
        if (v2f == v1f) j2 = A2; else j2 = B1;
        if (v3f == v2f) j3 = (v2f == v1f) ? A3 : B2;
        else            j3 = C1m;
        float ra = 1.0f / (v1f + 1e-8f);
        float rb = 1.0f / (v2f + 1e-8f);
        float rc = 1.0f / (v3f + 1e-8f);
        float sum = (ra + rb) + rc;
        size_t o = ((size_t)b * N_ + blockIdx.x * 128 + tid) * 3;
        nidx[o + 0] = j1; nidx[o + 1] = j2; nidx[o + 2] = j3;
        nw[o + 0] = ra / sum; nw[o + 1] = rb / sum; nw[o + 2] = rc / sum;
    }
}

// both weight tensors f32 -> bf16 in one launch
__global__ void cvtw_kernel(const float* __restrict__ w1, const float* __restrict__ w2,
                            unsigned short* __restrict__ w1b, unsigned short* __restrict__ w2b)
{
    int i = blockIdx.x * 256 + threadIdx.x;
    if (i < C1_ * CIN_) w1b[i] = f2bf(w1[i]);
    else {
        int j = i - C1_ * CIN_;
        if (j < C2_ * C1_) w2b[j] = f2bf(w2[j]);
    }
}

// ---------------------------------------------------------------------------
// bf16 MFMA GEMM + fused bias + fused BN-stats epilogue (round-6 proven,
// wall-faster than de-fused despite PMC replay inflation).
// MODE 1: A = relu(Abf*scale+shift), reg-staged.
// MODE 2: A = concat(p1, interp(p2)) built in-flight (fused a1build).
// ---------------------------------------------------------------------------
template <int K, int COUT, int WRITE_BF16, int MODE, int GRIDCOLS>
__global__ __launch_bounds__(256) void gemm_mfma_kernel(
    const unsigned short* __restrict__ Abf,  // [ROWS][K] bf16 (MODE 1)
    const unsigned short* __restrict__ W,    // [COUT][K] bf16
    const float* __restrict__ bias,          // [COUT]
    const float* __restrict__ scale,         // [K]  (MODE 1)
    const float* __restrict__ shift,         // [K]  (MODE 1)
    const float* __restrict__ p1,            // (MODE 2)
    const float* __restrict__ p2,            // (MODE 2)
    const int* __restrict__ nidx,            // (MODE 2)
    const float* __restrict__ nw,            // (MODE 2)
    void* __restrict__ out,                  // [ROWS][COUT] bf16 or f32
    float* __restrict__ sums, float* __restrict__ ssqs)
{
    __shared__ unsigned short As[4][128][8];   // 8 KiB
    __shared__ unsigned short Bs[4][128][8];   // 8 KiB
    __shared__ float csum[128], csq[128];
    const int tid = threadIdx.x;
    const int wave = tid >> 6, lane = tid & 63;
    const int chunkw = (blockIdx.x & 7) * (gridDim.x >> 3) + (blockIdx.x >> 3);
    const int r0 = (chunkw / GRIDCOLS) * 128;
    const int n0 = (chunkw % GRIDCOLS) * 128;
    const int wr = wave >> 1, wc = wave & 1;
    const int kh = lane >> 4, l16 = lane & 15;

    if (tid < 128) { csum[tid] = 0.f; csq[tid] = 0.f; }

    f32x4 acc[4][4];
#pragma unroll
    for (int m = 0; m < 4; ++m)
#pragma unroll
        for (int n = 0; n < 4; ++n)
            acc[m][n] = (f32x4){0.f, 0.f, 0.f, 0.f};

    const int slotbase = wave * 64;

    int rowA[2];
    int gj0[2], gj1[2], gj2[2];
    float gw0[2], gw1[2], gw2[2];
    const float* p2b = nullptr;
    if (MODE == 2) p2b = p2 + (size_t)(r0 >> 13) * S_ * D2_;
#pragma unroll
    for (int p = 0; p < 2; ++p) {
        const int s = p * 256 + slotbase + lane;
        rowA[p] = r0 + (s & 127);
        if (MODE == 2) {
            gj0[p] = nidx[rowA[p] * 3 + 0];
            gj1[p] = nidx[rowA[p] * 3 + 1];
            gj2[p] = nidx[rowA[p] * 3 + 2];
            gw0[p] = nw[rowA[p] * 3 + 0];
            gw1[p] = nw[rowA[p] * 3 + 1];
            gw2[p] = nw[rowA[p] * 3 + 2];
        }
    }

    for (int k0 = 0; k0 < K; k0 += 32) {
        __syncthreads();
#pragma unroll
        for (int p = 0; p < 2; ++p) {
            const int sb = p * 256 + slotbase;
            const int s = sb + lane;
            const int kg = s >> 7, i = s & 127;
            const unsigned short* gB = W + (size_t)(n0 + i) * K + k0 + kg * 8;
            __builtin_amdgcn_global_load_lds(
                (const __attribute__((address_space(1))) void*)gB,
                (__attribute__((address_space(3))) void*)(&Bs[0][0][0] + (size_t)sb * 8),
                16, 0, 0);
            const int c0 = k0 + kg * 8;
            short8v r;
            if (MODE == 1) {
                short8v v = *(const short8v*)(Abf + (size_t)rowA[p] * K + c0);
                float4 sca = *(const float4*)(scale + c0);
                float4 scb = *(const float4*)(scale + c0 + 4);
                float4 sha = *(const float4*)(shift + c0);
                float4 shb = *(const float4*)(shift + c0 + 4);
                float sc[8] = {sca.x, sca.y, sca.z, sca.w, scb.x, scb.y, scb.z, scb.w};
                float sh[8] = {sha.x, sha.y, sha.z, sha.w, shb.x, shb.y, shb.z, shb.w};
#pragma unroll
                for (int j = 0; j < 8; ++j) {
                    float f = bf2f((unsigned short)v[j]);
                    f = fmaxf(fmaf(f, sc[j], sh[j]), 0.0f);
                    r[j] = (short)f2bf(f);
                }
            } else {
                if (k0 < D1_) {
                    const float* qq = p1 + (size_t)rowA[p] * D1_ + c0;
                    float4 a = *(const float4*)qq;
                    float4 bq = *(const float4*)(qq + 4);
                    float t[8] = {a.x, a.y, a.z, a.w, bq.x, bq.y, bq.z, bq.w};
#pragma unroll
                    for (int j = 0; j < 8; ++j) r[j] = (short)f2bf(t[j]);
                } else {
                    const int cc = c0 - D1_;
                    const float* q0 = p2b + (size_t)gj0[p] * D2_ + cc;
                    const float* q1 = p2b + (size_t)gj1[p] * D2_ + cc;
                    const float* q2 = p2b + (size_t)gj2[p] * D2_ + cc;
                    float4 x0 = *(const float4*)q0, x0b = *(const float4*)(q0 + 4);
                    float4 x1 = *(const float4*)q1, x1b = *(const float4*)(q1 + 4);
                    float4 x2 = *(const float4*)q2, x2b = *(const float4*)(q2 + 4);
                    float a0[8] = {x0.x, x0.y, x0.z, x0.w, x0b.x, x0b.y, x0b.z, x0b.w};
                    float a1[8] = {x1.x, x1.y, x1.z, x1.w, x1b.x, x1b.y, x1b.z, x1b.w};
                    float a2[8] = {x2.x, x2.y, x2.z, x2.w, x2b.x, x2b.y, x2b.z, x2b.w};
                    const float w0 = gw0[p], w1 = gw1[p], w2 = gw2[p];
#pragma unroll
                    for (int j = 0; j < 8; ++j)
                        r[j] = (short)f2bf(a0[j] * w0 + a1[j] * w1 + a2[j] * w2);
                }
            }
            *(short8v*)&As[kg][i][0] = r;
        }
        __syncthreads();

        short8v af[4], bf[4];
#pragma unroll
        for (int m = 0; m < 4; ++m)
            af[m] = *(const short8v*)&As[kh][wr * 64 + m * 16 + l16][0];
#pragma unroll
        for (int n = 0; n < 4; ++n)
            bf[n] = *(const short8v*)&Bs[kh][wc * 64 + n * 16 + l16][0];
#pragma unroll
        for (int m = 0; m < 4; ++m)
#pragma unroll
            for (int n = 0; n < 4; ++n)
                acc[m][n] = __builtin_amdgcn_mfma_f32_16x16x32_bf16(
                    af[m], bf[n], acc[m][n], 0, 0, 0);
    }

#pragma unroll
    for (int n = 0; n < 4; ++n) {
        const int cl = wc * 64 + n * 16 + l16;
        const int col = n0 + cl;
        const float bv = bias[col];
        float s = 0.f, qs = 0.f;
#pragma unroll
        for (int m = 0; m < 4; ++m) {
            const int rowb = r0 + wr * 64 + m * 16 + kh * 4;
#pragma unroll
            for (int j = 0; j < 4; ++j) {
                const float v = acc[m][n][j] + bv;
                s += v; qs += v * v;
                if (WRITE_BF16)
                    ((unsigned short*)out)[(size_t)(rowb + j) * COUT + col] = f2bf(v);
                else
                    ((float*)out)[(size_t)(rowb + j) * COUT + col] = v;
            }
        }
        atomicAdd(&csum[cl], s);
        atomicAdd(&csq[cl], qs);
    }
    __syncthreads();
    if (tid < 128) {
        atomicAdd(&sums[n0 + tid], csum[tid]);
        atomicAdd(&ssqs[n0 + tid], csq[tid]);
    }
}

__global__ void finalize_kernel(const float* __restrict__ sums,
                                const float* __restrict__ ssqs,
                                const float* __restrict__ g,
                                const float* __restrict__ be,
                                float* __restrict__ scale,
                                float* __restrict__ shift, int C, float invCnt)
{
    int c = threadIdx.x;
    if (c < C) {
        float mu = sums[c] * invCnt;
        float var = ssqs[c] * invCnt - mu * mu;
        float sc = g[c] / sqrtf(var + 1e-5f);
        scale[c] = sc;
        shift[c] = be[c] - mu * sc;
    }
}

// final BN+ReLU, f32 out
__global__ __launch_bounds__(256) void bnrelu_store_kernel(
    const float* __restrict__ y, const float* __restrict__ scale,
    const float* __restrict__ shift, float* __restrict__ out)
{
    int i = blockIdx.x * 256 + threadIdx.x;   // float4 index
    float4 v = ((const float4*)y)[i];
    int o = (i * 4) & (C2_ - 1);
    float4 sc = *(const float4*)(scale + o);
    float4 sh = *(const float4*)(shift + o);
    float4 r;
    r.x = fmaxf(fmaf(v.x, sc.x, sh.x), 0.0f);
    r.y = fmaxf(fmaf(v.y, sc.y, sh.y), 0.0f);
    r.z = fmaxf(fmaf(v.z, sc.z, sh.z), 0.0f);
    r.w = fmaxf(fmaf(v.w, sc.w, sh.w), 0.0f);
    ((float4*)out)[i] = r;
}

extern "C" void kernel_launch(void* const* d_in, const int* in_sizes, int n_in,
                              void* d_out, int out_size, void* d_ws, size_t ws_size,
                              hipStream_t stream)
{
    const float* xyz1    = (const float*)d_in[0];
    const float* xyz2    = (const float*)d_in[1];
    const float* points1 = (const float*)d_in[2];
    const float* points2 = (const float*)d_in[3];
    const float* w1  = (const float*)d_in[4];
    const float* b1  = (const float*)d_in[5];
    const float* g1  = (const float*)d_in[6];
    const float* be1 = (const float*)d_in[7];
    const float* w2  = (const float*)d_in[8];
    const float* b2  = (const float*)d_in[9];
    const float* g2  = (const float*)d_in[10];
    const float* be2 = (const float*)d_in[11];
    float* out = (float*)d_out;

    char* w = (char*)d_ws;
    float*          y2  = (float*)w;                             // 33,554,432 B
    unsigned short* y1b = (unsigned short*)(w + 50331648);       // 33,554,432 B
    char* tail = w + 83886080;
    int*   nidx = (int*)tail;                                    // 786,432 B
    float* nw   = (float*)(tail + 786432);                       // 786,432 B
    unsigned short* w1b = (unsigned short*)(tail + 1572864);     // 196,608 B
    unsigned short* w2b = (unsigned short*)(tail + 1769472);     // 65,536 B
    float* sum1   = (float*)(tail + 1835008);
    float* ssq1   = sum1 + 256;
    float* sum2   = ssq1 + 256;
    float* ssq2   = sum2 + 128;
    float* scale1 = ssq2 + 128;
    float* shift1 = scale1 + 256;
    float* scale2 = shift1 + 256;
    float* shift2 = scale2 + 128;
    float4* pk    = (float4*)(tail + 1843200);                   // 262,144 B

    hipMemsetAsync(sum1, 0, (256 + 256 + 128 + 128) * sizeof(float), stream);

    cvtw_kernel<<<dim3((C1_ * CIN_ + C2_ * C1_ + 255) / 256), 256, 0, stream>>>(w1, w2, w1b, w2b);
    pack_kernel<<<dim3(B_ * S_ / 256), 256, 0, stream>>>(xyz2, pk);

    nn3_kernel<<<dim3(N_ / 128, B_), 1024, 0, stream>>>(xyz1, pk, nidx, nw);

    // GEMM1: fused concat+interp A-build, bias, BN-stats
    gemm_mfma_kernel<CIN_, C1_, 1, 2, 2><<<dim3(ROWS_ / 128 * 2), 256, 0, stream>>>(
        nullptr, w1b, b1, nullptr, nullptr, points1, points2, nidx, nw,
        (void*)y1b, sum1, ssq1);
    finalize_kernel<<<1, 256, 0, stream>>>(sum1, ssq1, g1, be1, scale1, shift1, C1_, 1.0f / ROWS_);

    // GEMM2: BN+ReLU fused on A-load, bias, BN-stats
    gemm_mfma_kernel<C1_, C2_, 0, 1, 1><<<dim3(ROWS_ / 128), 256, 0, stream>>>(
        y1b, w2b, b2, scale1, shift1, nullptr, nullptr, nullptr, nullptr,
        (void*)y2, sum2, ssq2);
    finalize_kernel<<<1, 256, 0, stream>>>(sum2, ssq2, g2, be2, scale2, shift2, C2_, 1.0f / ROWS_);

    bnrelu_store_kernel<<<dim3(ROWS_ * C2_ / 4 / 256), 256, 0, stream>>>(y2, scale2, shift2, out);
}